// Round 1
// baseline (443.309 us; speedup 1.0000x reference)
//
#include <hip/hip_runtime.h>
#include <hip/hip_bf16.h>
#include <stdint.h>

typedef __bf16 bf16x8 __attribute__((ext_vector_type(8)));
typedef float f32x4 __attribute__((ext_vector_type(4)));

#define B_DIM 16
#define TD 1024
#define TE 1024
#define DD 1024

__device__ __forceinline__ uint32_t rne_bf16(float x) {
  uint32_t u = __builtin_bit_cast(uint32_t, x);
  return (u + 0x7FFFu + ((u >> 16) & 1u)) >> 16;
}

// ---------------------------------------------------------------------------
// K1: S[t][e] = sum_d dec[b,t,d] * enc[b,e,d], fp32-accurate via bf16 hi/lo
// split (Ah*Bh + Ah*Bl + Al*Bh). 128x128 C-tile, BK=32, 4 waves in 2x2,
// each wave 4x4 grid of 16x16x32 MFMAs. S written to out[b, t, 1024+e].
// ---------------------------------------------------------------------------
__global__ __launch_bounds__(256, 2)
void k1_scores(const float* __restrict__ dec, const float* __restrict__ enc,
               float* __restrict__ out) {
  __shared__ uint32_t AhU[2048], AlU[2048], BhU[2048], BlU[2048];  // 4 x 8KB
  const int tid = threadIdx.x;
  const int lane = tid & 63;
  const int wave = tid >> 6;
  const int wm = wave >> 1, wn = wave & 1;
  const int b = blockIdx.z;
  const int t0 = blockIdx.y * 128, e0 = blockIdx.x * 128;
  const float* A = dec + (size_t)b * TD * DD;
  const float* Bm = enc + (size_t)b * TE * DD;

  // staging: thread covers float4 chunk f = tid + 256*s; row r=f>>3, col4 f&7
  const int r = tid >> 3, c4 = tid & 7;
  const float* aptr = A + (size_t)(t0 + r) * DD + c4 * 4;
  const float* bptr = Bm + (size_t)(e0 + r) * DD + c4 * 4;

  const int lr = lane & 15, q = lane >> 4;
  int aoff[4], boff[4];
#pragma unroll
  for (int i = 0; i < 4; ++i) {
    aoff[i] = (wm * 64 + i * 16 + lr) * 16 + q * 4;  // dword offsets
    boff[i] = (wn * 64 + i * 16 + lr) * 16 + q * 4;
  }

  f32x4 acc[4][4] = {};

  for (int k0 = 0; k0 < DD; k0 += 32) {
#pragma unroll
    for (int s = 0; s < 4; ++s) {
      const float4 va = *(const float4*)(aptr + (size_t)(32 * s) * DD);
      const float4 vb = *(const float4*)(bptr + (size_t)(32 * s) * DD);
      const int woff = (r + 32 * s) * 16 + c4 * 2;
      {
        uint32_t u0 = __builtin_bit_cast(uint32_t, va.x);
        uint32_t u1 = __builtin_bit_cast(uint32_t, va.y);
        uint32_t u2 = __builtin_bit_cast(uint32_t, va.z);
        uint32_t u3 = __builtin_bit_cast(uint32_t, va.w);
        uint32_t m0 = u0 & 0xFFFF0000u, m1 = u1 & 0xFFFF0000u;
        uint32_t m2 = u2 & 0xFFFF0000u, m3 = u3 & 0xFFFF0000u;
        float l0 = va.x - __builtin_bit_cast(float, m0);
        float l1 = va.y - __builtin_bit_cast(float, m1);
        float l2 = va.z - __builtin_bit_cast(float, m2);
        float l3 = va.w - __builtin_bit_cast(float, m3);
        *(uint2*)&AhU[woff] = make_uint2((m0 >> 16) | m1, (m2 >> 16) | m3);
        *(uint2*)&AlU[woff] = make_uint2(
            (__builtin_bit_cast(uint32_t, l0) >> 16) |
                (__builtin_bit_cast(uint32_t, l1) & 0xFFFF0000u),
            (__builtin_bit_cast(uint32_t, l2) >> 16) |
                (__builtin_bit_cast(uint32_t, l3) & 0xFFFF0000u));
      }
      {
        uint32_t u0 = __builtin_bit_cast(uint32_t, vb.x);
        uint32_t u1 = __builtin_bit_cast(uint32_t, vb.y);
        uint32_t u2 = __builtin_bit_cast(uint32_t, vb.z);
        uint32_t u3 = __builtin_bit_cast(uint32_t, vb.w);
        uint32_t m0 = u0 & 0xFFFF0000u, m1 = u1 & 0xFFFF0000u;
        uint32_t m2 = u2 & 0xFFFF0000u, m3 = u3 & 0xFFFF0000u;
        float l0 = vb.x - __builtin_bit_cast(float, m0);
        float l1 = vb.y - __builtin_bit_cast(float, m1);
        float l2 = vb.z - __builtin_bit_cast(float, m2);
        float l3 = vb.w - __builtin_bit_cast(float, m3);
        *(uint2*)&BhU[woff] = make_uint2((m0 >> 16) | m1, (m2 >> 16) | m3);
        *(uint2*)&BlU[woff] = make_uint2(
            (__builtin_bit_cast(uint32_t, l0) >> 16) |
                (__builtin_bit_cast(uint32_t, l1) & 0xFFFF0000u),
            (__builtin_bit_cast(uint32_t, l2) >> 16) |
                (__builtin_bit_cast(uint32_t, l3) & 0xFFFF0000u));
      }
    }
    __syncthreads();

    bf16x8 ah[4], al[4];
#pragma unroll
    for (int mi = 0; mi < 4; ++mi) {
      ah[mi] = *(const bf16x8*)&AhU[aoff[mi]];
      al[mi] = *(const bf16x8*)&AlU[aoff[mi]];
    }
#pragma unroll
    for (int ni = 0; ni < 4; ++ni) {
      bf16x8 bh = *(const bf16x8*)&BhU[boff[ni]];
      bf16x8 bl = *(const bf16x8*)&BlU[boff[ni]];
#pragma unroll
      for (int mi = 0; mi < 4; ++mi) {
        f32x4 c = acc[mi][ni];
        c = __builtin_amdgcn_mfma_f32_16x16x32_bf16(al[mi], bh, c, 0, 0, 0);
        c = __builtin_amdgcn_mfma_f32_16x16x32_bf16(ah[mi], bl, c, 0, 0, 0);
        c = __builtin_amdgcn_mfma_f32_16x16x32_bf16(ah[mi], bh, c, 0, 0, 0);
        acc[mi][ni] = c;
      }
    }
    __syncthreads();
    aptr += 32;
    bptr += 32;
  }

  // C/D layout: col(n=e) = lane&15, row(m=t) = (lane>>4)*4 + reg
  float* outb = out + (size_t)b * TD * 2048 + 1024;
  const int tb = t0 + wm * 64 + q * 4;
  const int eb = e0 + wn * 64 + lr;
#pragma unroll
  for (int mi = 0; mi < 4; ++mi)
#pragma unroll
    for (int ni = 0; ni < 4; ++ni)
#pragma unroll
      for (int i = 0; i < 4; ++i)
        outb[(size_t)(tb + mi * 16 + i) * 2048 + (eb + ni * 16)] = acc[mi][ni][i];
}

// ---------------------------------------------------------------------------
// K2: softmax over e for each (b,t) row. Reads fp32 S from out[row, 1024:2048],
// writes bf16 P (1024 elems = 2KB) into the FIRST half of the row.
// One wave per row, 4 rows per block.
// ---------------------------------------------------------------------------
__global__ __launch_bounds__(256)
void k2_softmax(float* out) {
  const int lane = threadIdx.x & 63;
  const int row = blockIdx.x * 4 + (threadIdx.x >> 6);
  float* Srow = out + (size_t)row * 2048 + 1024;
  float4 v[4];
#pragma unroll
  for (int s = 0; s < 4; ++s) v[s] = *(const float4*)(Srow + lane * 4 + s * 256);
  float m = -1e30f;
#pragma unroll
  for (int s = 0; s < 4; ++s)
    m = fmaxf(m, fmaxf(fmaxf(v[s].x, v[s].y), fmaxf(v[s].z, v[s].w)));
#pragma unroll
  for (int o = 32; o > 0; o >>= 1) m = fmaxf(m, __shfl_xor(m, o));
  float e[16];
  float sum = 0.f;
#pragma unroll
  for (int s = 0; s < 4; ++s) {
    e[4 * s + 0] = __expf(v[s].x - m);
    e[4 * s + 1] = __expf(v[s].y - m);
    e[4 * s + 2] = __expf(v[s].z - m);
    e[4 * s + 3] = __expf(v[s].w - m);
    sum += e[4 * s + 0] + e[4 * s + 1] + e[4 * s + 2] + e[4 * s + 3];
  }
#pragma unroll
  for (int o = 32; o > 0; o >>= 1) sum += __shfl_xor(sum, o);
  const float inv = 1.0f / sum;
  uint32_t* Prow = (uint32_t*)(out + (size_t)row * 2048);
#pragma unroll
  for (int s = 0; s < 4; ++s) {
    uint32_t r0 = rne_bf16(e[4 * s + 0] * inv);
    uint32_t r1 = rne_bf16(e[4 * s + 1] * inv);
    uint32_t r2 = rne_bf16(e[4 * s + 2] * inv);
    uint32_t r3 = rne_bf16(e[4 * s + 3] * inv);
    *(uint2*)&Prow[lane * 2 + s * 128] =
        make_uint2(r0 | (r1 << 16), r2 | (r3 << 16));
  }
}

// ---------------------------------------------------------------------------
// K3: ctx[t][d] = sum_e P[t][e] * enc[e][d], plain bf16 MFMA.
// A = P (bf16, rows at out first half, row stride 4096 bf16).
// B = enc fp32, transposed+RNE-converted at staging into Bt[d][e] (row 40
// bf16 = 80B padded, keeps ds_read_b128 16B-aligned). Writes out[b,t,1024+d].
// ---------------------------------------------------------------------------
__global__ __launch_bounds__(256, 2)
void k3_av(const float* __restrict__ enc, float* __restrict__ out) {
  __shared__ uint32_t AU[2048];       // [128 t][32 e] bf16
  __shared__ uint32_t BtU[128 * 20];  // [128 d][40 bf16] (32 used + pad)
  const int tid = threadIdx.x;
  const int lane = tid & 63, wave = tid >> 6;
  const int wm = wave >> 1, wn = wave & 1;
  const int b = blockIdx.z;
  const int t0 = blockIdx.y * 128, d0 = blockIdx.x * 128;
  const float* V = enc + (size_t)b * TE * DD;
  const uint16_t* Pb = (const uint16_t*)(out + (size_t)b * TD * 2048);
  const int lr = lane & 15, q = lane >> 4;
  int aoff[4], boff[4];
#pragma unroll
  for (int i = 0; i < 4; ++i) {
    aoff[i] = (wm * 64 + i * 16 + lr) * 16 + q * 4;
    boff[i] = (wn * 64 + i * 16 + lr) * 20 + q * 4;
  }
  const int dB = tid & 127;
  f32x4 acc[4][4] = {};

  for (int e0k = 0; e0k < TE; e0k += 32) {
    // A tile: 8KB of bf16 P, 16B chunks
#pragma unroll
    for (int s = 0; s < 2; ++s) {
      int c = tid + 256 * s;
      int rc = c >> 2, cc = c & 3;
      uint4 va = *(const uint4*)(Pb + (size_t)(t0 + rc) * 4096 + e0k + cc * 8);
      *(uint4*)&AU[c * 4] = va;
    }
    // B tile: enc[e0k:e0k+32][d0:d0+128] fp32 -> transpose -> Bt[d][e] bf16
#pragma unroll
    for (int s = 0; s < 4; ++s) {
      int eg = (tid >> 7) + 2 * s;
      const float* src = V + (size_t)(e0k + eg * 4) * DD + d0 + dB;
      float x0 = src[0], x1 = src[DD], x2 = src[2 * DD], x3 = src[3 * DD];
      uint32_t r0 = rne_bf16(x0), r1 = rne_bf16(x1);
      uint32_t r2 = rne_bf16(x2), r3 = rne_bf16(x3);
      *(uint2*)&BtU[dB * 20 + eg * 2] =
          make_uint2(r0 | (r1 << 16), r2 | (r3 << 16));
    }
    __syncthreads();

    bf16x8 af[4];
#pragma unroll
    for (int mi = 0; mi < 4; ++mi) af[mi] = *(const bf16x8*)&AU[aoff[mi]];
#pragma unroll
    for (int ni = 0; ni < 4; ++ni) {
      bf16x8 bfr = *(const bf16x8*)&BtU[boff[ni]];
#pragma unroll
      for (int mi = 0; mi < 4; ++mi)
        acc[mi][ni] =
            __builtin_amdgcn_mfma_f32_16x16x32_bf16(af[mi], bfr, acc[mi][ni], 0, 0, 0);
    }
    __syncthreads();
  }

  float* outb = out + (size_t)b * TD * 2048 + 1024;
  const int tb = t0 + wm * 64 + q * 4;
  const int db = d0 + wn * 64 + lr;
#pragma unroll
  for (int mi = 0; mi < 4; ++mi)
#pragma unroll
    for (int ni = 0; ni < 4; ++ni)
#pragma unroll
      for (int i = 0; i < 4; ++i)
        outb[(size_t)(tb + mi * 16 + i) * 2048 + (db + ni * 16)] = acc[mi][ni][i];
}

// ---------------------------------------------------------------------------
// K4: copy decoder_outputs into out[b,t,0:1024] (after K3 consumed P).
// ---------------------------------------------------------------------------
__global__ __launch_bounds__(256)
void k4_copydec(const float4* __restrict__ dec4, float4* __restrict__ out4) {
  size_t g = (size_t)blockIdx.x * 512 + threadIdx.x;
#pragma unroll
  for (int s = 0; s < 2; ++s, g += 256) {
    size_t row = g >> 8, col = g & 255;  // 256 float4 per 1024-float row
    out4[row * 512 + col] = dec4[g];
  }
}

extern "C" void kernel_launch(void* const* d_in, const int* in_sizes, int n_in,
                              void* d_out, int out_size, void* d_ws, size_t ws_size,
                              hipStream_t stream) {
  // setup_inputs order: [0]=encoder_outputs, [1]=decoder_outputs (fp32)
  const float* enc = (const float*)d_in[0];
  const float* dec = (const float*)d_in[1];
  float* out = (float*)d_out;

  hipLaunchKernelGGL(k1_scores, dim3(8, 8, 16), dim3(256), 0, stream, dec, enc, out);
  hipLaunchKernelGGL(k2_softmax, dim3(4096), dim3(256), 0, stream, out);
  hipLaunchKernelGGL(k3_av, dim3(8, 8, 16), dim3(256), 0, stream, enc, out);
  hipLaunchKernelGGL(k4_copydec, dim3(8192), dim3(256), 0, stream,
                     (const float4*)dec, (float4*)out);
}